// Round 6
// baseline (87.842 us; speedup 1.0000x reference)
//
#include <hip/hip_runtime.h>
#include <cstdint>
#include <cstddef>

// ---------------------------------------------------------------------------
// BasicLSTM fused kernel for MI355X (gfx950) — round 6.
//   pre_g = X @ W_g + H @ u_g + b_g   for g in {f, i, o}
//   c_new = sig(pre_f)*c0 + sig(pre_f)*sig(pre_i)     (input_cell == forget!)
//   h_new = sig(pre_o)*tanh(c_new)
// Round-6 change vs round 5: raise arithmetic intensity per LDS byte.
//   4 waves (256 thr), wave tile 64x64 per gate (was 8 waves, 64x32):
//   reads/MFMA drops 0.417 -> 0.333, so per step DS ~1020 cyc < MFMA 931+..
//   -> MFMA becomes the long pole instead of LDS.
//   Same 128x128 block tile (grid 256 = CU count), same swizzle (verified
//   conflict-free), same ring-4 + counted vmcnt + reg double-buffer.
// ---------------------------------------------------------------------------

typedef __attribute__((ext_vector_type(8))) short bf16x8;
typedef __attribute__((ext_vector_type(4))) float f32x4;
typedef __attribute__((ext_vector_type(8))) short s16x8;
typedef __attribute__((ext_vector_type(4))) float f32x4v;

#define MROWS 4096
#define KDIM  1024   // D == S == 1024
#define NCOLS 1024

__device__ __forceinline__ short f2bf(float f) {
    uint32_t u = __builtin_bit_cast(uint32_t, f);
    u += 0x7fffu + ((u >> 16) & 1u);   // round-to-nearest-even
    return (short)(u >> 16);
}

// ---- fp32 -> bf16 for X and H in one launch (32B in / 16B out per thread) --
__global__ void cvt_bf16_kernel(const float* __restrict__ x,
                                const float* __restrict__ h,
                                short* __restrict__ xb,
                                short* __restrict__ hb) {
    int b = blockIdx.x;
    const float* in;
    short* out;
    if (b < 2048) { in = x; out = xb; }
    else          { in = h; out = hb; b -= 2048; }
    const int i = (b * 256 + threadIdx.x) * 8;
    f32x4v a = *(const f32x4v*)(in + i);
    f32x4v c = *(const f32x4v*)(in + i + 4);
    s16x8 o;
    o[0] = f2bf(a[0]); o[1] = f2bf(a[1]); o[2] = f2bf(a[2]); o[3] = f2bf(a[3]);
    o[4] = f2bf(c[0]); o[5] = f2bf(c[1]); o[6] = f2bf(c[2]); o[7] = f2bf(c[3]);
    *(s16x8*)(out + i) = o;
}

// ---- transpose + convert all 6 weights: w [K][N] fp32 -> wt [N][K] bf16 ----
struct W6 {
    const float* src[6];
    short* dst[6];
};

__global__ void transpose_cvt_kernel(W6 p) {
    __shared__ short tile[32][33];
    const float* __restrict__ w  = p.src[blockIdx.z];
    short* __restrict__       wt = p.dst[blockIdx.z];
    const int tx = threadIdx.x & 31;
    const int ty = threadIdx.x >> 5;          // 0..7
    const int kbase = blockIdx.y * 32;
    const int nbase = blockIdx.x * 32;
#pragma unroll
    for (int r = 0; r < 4; ++r) {
        int k = kbase + ty + r * 8;
        tile[ty + r * 8][tx] = f2bf(w[k * NCOLS + nbase + tx]);
    }
    __syncthreads();
#pragma unroll
    for (int r = 0; r < 4; ++r) {
        int n = nbase + ty + r * 8;
        wt[n * KDIM + kbase + tx] = tile[tx][ty + r * 8];
    }
}

// ---- fused 3-gate GEMM + LSTM cell ----
// Block: 256 threads = 4 waves (2M x 2N). Block tile 128x128, 3 gates fused.
// Wave tile 64x64 per gate: 16 ds_read_b128 feed 48 MFMAs per K-step.
// BK = 32, 64 K-steps over [X|H] x [W|U]. 4-deep LDS ring (4 x 32 KB).
// LDS image per tile r (0=A,1..3=B gate): 128 rows x 4 chunks of 16B,
// chunk slot rotated by (row>>1)&3 for conflict-free ds_read_b128.
__global__ __launch_bounds__(256, 1)
void lstm_gemm_kernel(const short* __restrict__ Xb, const short* __restrict__ Hb,
                      const short* __restrict__ WT0, const short* __restrict__ WT1,
                      const short* __restrict__ WT2,
                      const short* __restrict__ UT0, const short* __restrict__ UT1,
                      const short* __restrict__ UT2,
                      const float* __restrict__ bf_, const float* __restrict__ bi_,
                      const float* __restrict__ bo_,
                      const float* __restrict__ c0,
                      float* __restrict__ outH, float* __restrict__ outC) {
    __shared__ __align__(16) short lds[4][16384];   // 4 x 32 KB ring

    const int tid  = threadIdx.x;
    const int lane = tid & 63;
    const int wave = tid >> 6;            // 0..3
    const int wm   = wave >> 1;           // 0..1  (row group, 64 rows each)
    const int wn   = wave & 1;            // 0..1  (col group, 64 cols each)
    const int m0   = blockIdx.y * 128;
    const int n0   = blockIdx.x * 128;

    const int l15 = lane & 15;
    const int q   = lane >> 4;            // k-chunk index of this lane

    f32x4 acc[3][4][4] = {};   // [gate][m][n] = 192 VGPRs

    // staging: thread tid stages LDS slots tid and tid+256 (16B each) of each
    // tile. slot s: row s>>2, chunk-slot s&3, holds global chunk
    // (s&3)^((row>>1)&3). Both slots share the same rotation (row2=row+64).
    const int srow   = tid >> 2;                       // 0..63
    const int schunk = (tid & 3) ^ ((tid >> 3) & 3);
    const int skoff  = schunk * 8;                     // element offset in row

    // precomputed swizzled read byte-offsets within a tile
    int aOff[4], bOff[4];
#pragma unroll
    for (int m = 0; m < 4; ++m) {
        const int row = wm * 64 + m * 16 + l15;
        aOff[m] = row * 64 + ((q ^ ((row >> 1) & 3)) << 4);
    }
#pragma unroll
    for (int n = 0; n < 4; ++n) {
        const int row = wn * 64 + n * 16 + l15;
        bOff[n] = row * 64 + ((q ^ ((row >> 1) & 3)) << 4);
    }

    auto stage = [&](int buf, int kt) {
        const bool second = kt >= 32;
        const short* aS = second ? Hb  : Xb;
        const short* s0 = second ? UT0 : WT0;
        const short* s1 = second ? UT1 : WT1;
        const short* s2 = second ? UT2 : WT2;
        const int kk = (kt & 31) * 32 + skoff;
#pragma unroll
        for (int r = 0; r < 4; ++r) {
            const short* src = (r == 0) ? aS : (r == 1 ? s0 : (r == 2 ? s1 : s2));
            const int rbase = (r == 0) ? m0 : n0;
            const char* g0 = (const char*)(src + (size_t)(rbase + srow) * KDIM + kk);
            const char* g1 = (const char*)(src + (size_t)(rbase + srow + 64) * KDIM + kk);
            __builtin_amdgcn_global_load_lds(
                (const __attribute__((address_space(1))) unsigned int*)(uintptr_t)g0,
                (__attribute__((address_space(3))) unsigned int*)(uintptr_t)
                    ((char*)&lds[buf][0] + r * 8192 + tid * 16),
                16, 0, 0);
            __builtin_amdgcn_global_load_lds(
                (const __attribute__((address_space(1))) unsigned int*)(uintptr_t)g1,
                (__attribute__((address_space(3))) unsigned int*)(uintptr_t)
                    ((char*)&lds[buf][0] + r * 8192 + 4096 + tid * 16),
                16, 0, 0);
        }
    };

    // fragment register sets (double-buffered, statically indexed)
    bf16x8 fa0[4], fb0[12], fa1[4], fb1[12];

#define READF(FA, FB, BUF)                                                   \
    {                                                                        \
        const char* L_ = (const char*)&lds[(BUF)][0];                        \
        _Pragma("unroll")                                                    \
        for (int m_ = 0; m_ < 4; ++m_)                                       \
            FA[m_] = *(const bf16x8*)(L_ + aOff[m_]);                        \
        _Pragma("unroll")                                                    \
        for (int g_ = 0; g_ < 3; ++g_)                                       \
            _Pragma("unroll")                                                \
            for (int n_ = 0; n_ < 4; ++n_)                                   \
                FB[g_ * 4 + n_] =                                            \
                    *(const bf16x8*)(L_ + 8192 * (1 + g_) + bOff[n_]);       \
    }

#define MFMAC(FA, FB)                                                        \
    {                                                                        \
        __builtin_amdgcn_s_setprio(1);                                       \
        _Pragma("unroll")                                                    \
        for (int g_ = 0; g_ < 3; ++g_)                                       \
            _Pragma("unroll")                                                \
            for (int n_ = 0; n_ < 4; ++n_)                                   \
                _Pragma("unroll")                                            \
                for (int m_ = 0; m_ < 4; ++m_)                               \
                    acc[g_][m_][n_] = __builtin_amdgcn_mfma_f32_16x16x32_bf16(\
                        FA[m_], FB[g_ * 4 + n_], acc[g_][m_][n_], 0, 0, 0);  \
        __builtin_amdgcn_s_setprio(0);                                       \
    }

#define WAITV(N) asm volatile("s_waitcnt vmcnt(" #N ")" ::: "memory")
#define WAITL0   asm volatile("s_waitcnt lgkmcnt(0)" ::: "memory")
#define BAR      __builtin_amdgcn_s_barrier()
#define SCHED0   __builtin_amdgcn_sched_barrier(0)

    // prologue: 3 tiles in flight (8 loads each), frags(0) in set 0
    stage(0, 0);
    stage(1, 1);
    stage(2, 2);
    WAITV(16);         // tile 0 landed (16 = tiles 1,2 in flight)
    BAR;
    SCHED0;
    READF(fa0, fb0, 0);
    WAITL0;

    // main loop. Body kt: wait tile kt+1; read its frags into the alternate
    // set; stage tile kt+3; MFMA tile kt (stage VALU free to interleave with
    // the MFMA cluster — only READF is order-pinned).
    for (int kt = 0; kt < 60; kt += 2) {
        // body A (even kt): MFMA set0, read set1
        WAITV(8);                      // tile kt+1 landed
        BAR;
        SCHED0;
        READF(fa1, fb1, (kt + 1) & 3);
        SCHED0;
        stage((kt + 3) & 3, kt + 3);
        MFMAC(fa0, fb0);
        WAITL0;                        // ring WAR safety before next barrier
        // body B (odd): MFMA set1, read set0
        WAITV(8);                      // tile kt+2 landed
        BAR;
        SCHED0;
        READF(fa0, fb0, (kt + 2) & 3);
        SCHED0;
        stage((kt + 4) & 3, kt + 4);
        MFMAC(fa1, fb1);
        WAITL0;
    }

    // tail kt = 60..63
    WAITV(8);          // tile 61 landed
    BAR;
    SCHED0;
    READF(fa1, fb1, 61 & 3);
    SCHED0;
    stage(63 & 3, 63);
    MFMAC(fa0, fb0);   // kt=60
    WAITL0;

    WAITV(8);          // tile 62 landed
    BAR;
    SCHED0;
    READF(fa0, fb0, 62 & 3);
    SCHED0;
    MFMAC(fa1, fb1);   // kt=61
    WAITL0;

    WAITV(0);          // tile 63 landed
    BAR;
    SCHED0;
    READF(fa1, fb1, 63 & 3);
    SCHED0;
    MFMAC(fa0, fb0);   // kt=62
    WAITL0;

    MFMAC(fa1, fb1);   // kt=63

    // ---- fused LSTM epilogue ----
    const int rj = (lane >> 4) * 4;   // row sub-offset within 16x16 frag
#pragma unroll
    for (int m = 0; m < 4; ++m) {
#pragma unroll
        for (int n = 0; n < 4; ++n) {
            const int col = n0 + wn * 64 + n * 16 + l15;
            const float bfv = bf_[col], biv = bi_[col], bov = bo_[col];
            const f32x4 pf = acc[0][m][n];
            const f32x4 pi = acc[1][m][n];
            const f32x4 po = acc[2][m][n];
#pragma unroll
            for (int j = 0; j < 4; ++j) {
                const int row = m0 + wm * 64 + m * 16 + rj + j;
                const float fg = 1.f / (1.f + __expf(-(pf[j] + bfv)));
                const float ig = 1.f / (1.f + __expf(-(pi[j] + biv)));
                const float og = 1.f / (1.f + __expf(-(po[j] + bov)));
                const float cv = c0[row * NCOLS + col];
                const float cn = fg * cv + fg * ig;   // input_cell == forget gate
                const float e  = __expf(-2.f * cn);
                const float th = (1.f - e) / (1.f + e);
                outH[row * NCOLS + col] = og * th;
                outC[row * NCOLS + col] = cn;
            }
        }
    }
#undef READF
#undef MFMAC
#undef WAITV
#undef WAITL0
#undef BAR
#undef SCHED0
}

extern "C" void kernel_launch(void* const* d_in, const int* in_sizes, int n_in,
                              void* d_out, int out_size, void* d_ws, size_t ws_size,
                              hipStream_t stream) {
    const float* inputs = (const float*)d_in[0];
    const float* h0     = (const float*)d_in[1];
    const float* c0     = (const float*)d_in[2];
    const float* w_f    = (const float*)d_in[3];
    const float* u_f    = (const float*)d_in[4];
    const float* b_f    = (const float*)d_in[5];
    const float* w_i    = (const float*)d_in[6];
    const float* u_i    = (const float*)d_in[7];
    const float* b_i    = (const float*)d_in[8];
    const float* w_o    = (const float*)d_in[9];
    const float* u_o    = (const float*)d_in[10];
    const float* b_o    = (const float*)d_in[11];

    float* outH = (float*)d_out;
    float* outC = outH + (size_t)MROWS * NCOLS;

    // workspace (bf16): Xb 8MB | Hb 8MB | WT0..2 2MB each | UT0..2 2MB each
    char* ws = (char*)d_ws;
    short* Xb  = (short*)(ws);
    short* Hb  = (short*)(ws + (8u << 20));
    short* WT0 = (short*)(ws + (16u << 20));
    short* WT1 = (short*)(ws + (18u << 20));
    short* WT2 = (short*)(ws + (20u << 20));
    short* UT0 = (short*)(ws + (22u << 20));
    short* UT1 = (short*)(ws + (24u << 20));
    short* UT2 = (short*)(ws + (26u << 20));

    // X and H conversion in one launch (2048 blocks each)
    cvt_bf16_kernel<<<4096, 256, 0, stream>>>(inputs, h0, Xb, Hb);

    // all 6 weight transposes in one launch
    W6 p;
    p.src[0] = w_f; p.src[1] = w_i; p.src[2] = w_o;
    p.src[3] = u_f; p.src[4] = u_i; p.src[5] = u_o;
    p.dst[0] = WT0; p.dst[1] = WT1; p.dst[2] = WT2;
    p.dst[3] = UT0; p.dst[4] = UT1; p.dst[5] = UT2;
    transpose_cvt_kernel<<<dim3(32, 32, 6), 256, 0, stream>>>(p);

    dim3 grid(NCOLS / 128, MROWS / 128);   // (8, 32) = 256 blocks
    lstm_gemm_kernel<<<grid, 256, 0, stream>>>(
        Xb, Hb, WT0, WT1, WT2, UT0, UT1, UT2,
        b_f, b_i, b_o, c0, outH, outC);
}

// Round 7
// 80.092 us; speedup vs baseline: 1.0968x; 1.0968x over previous
//
#include <hip/hip_runtime.h>
#include <cstdint>
#include <cstddef>

// ---------------------------------------------------------------------------
// BasicLSTM fused kernel for MI355X (gfx950) — round 7.
//   pre_g = X @ W_g + H @ U_g + b_g   for g in {f, i, o}
//   c_new = sig(pre_f)*c0 + sig(pre_f)*sig(pre_i)     (input_cell == forget!)
//   h_new = sig(pre_o)*tanh(c_new)
// Round-7 change vs round 5/6: B operand bypasses LDS entirely.
//  - Weights pre-packed to MFMA-fragment-linear layout: for each (16-col tile
//    t, 32-k chunk c): 64 lanes x 16B contiguous. A wave's B-frag load is ONE
//    coalesced global_load_dwordx4 -> registers (reg ring, prefetch 1 step).
//  - grid(8,32): linear block id % 8 = n-index -> same-n0 blocks share an XCD
//    -> 1.5MB weight slice L2-resident per XCD.
//  - LDS now holds only A (ring-4 x 8KB): traffic/step drops 112KB -> 40KB;
//    MFMA (931 cyc/step/CU) becomes the long pole.
//  - 8 waves (512 thr) restored: 2 waves/SIMD for latency hiding (R6 lesson).
// ---------------------------------------------------------------------------

typedef __attribute__((ext_vector_type(8))) short bf16x8;
typedef __attribute__((ext_vector_type(4))) float f32x4;
typedef __attribute__((ext_vector_type(8))) short s16x8;
typedef __attribute__((ext_vector_type(4))) float f32x4v;

#define MROWS 4096
#define KDIM  1024   // D == S == 1024
#define NCOLS 1024

__device__ __forceinline__ short f2bf(float f) {
    uint32_t u = __builtin_bit_cast(uint32_t, f);
    u += 0x7fffu + ((u >> 16) & 1u);   // round-to-nearest-even
    return (short)(u >> 16);
}

// ---- fp32 -> bf16 for X and H in one launch (32B in / 16B out per thread) --
__global__ void cvt_bf16_kernel(const float* __restrict__ x,
                                const float* __restrict__ h,
                                short* __restrict__ xb,
                                short* __restrict__ hb) {
    int b = blockIdx.x;
    const float* in;
    short* out;
    if (b < 2048) { in = x; out = xb; }
    else          { in = h; out = hb; b -= 2048; }
    const int i = (b * 256 + threadIdx.x) * 8;
    f32x4v a = *(const f32x4v*)(in + i);
    f32x4v c = *(const f32x4v*)(in + i + 4);
    s16x8 o;
    o[0] = f2bf(a[0]); o[1] = f2bf(a[1]); o[2] = f2bf(a[2]); o[3] = f2bf(a[3]);
    o[4] = f2bf(c[0]); o[5] = f2bf(c[1]); o[6] = f2bf(c[2]); o[7] = f2bf(c[3]);
    *(s16x8*)(out + i) = o;
}

// ---- transpose + convert + PACK all 6 weights ----
// w [K][N] fp32 -> wp packed bf16: for col-tile t (16 cols), k-chunk c (32 k):
//   element ((t*32 + c)*64 + lane)*8 + j  holds  w[c*32 + (lane>>4)*8 + j][t*16 + (lane&15)]
// i.e. exactly the 16B/lane the MFMA B-fragment read wants, contiguous.
struct W6 {
    const float* src[6];
    short* dst[6];
};

__global__ void transpose_cvt_kernel(W6 p) {
    __shared__ short tile[32][33];   // [k_local][n_local]
    const float* __restrict__ w  = p.src[blockIdx.z];
    short* __restrict__       wp = p.dst[blockIdx.z];
    const int tx = threadIdx.x & 31;
    const int ty = threadIdx.x >> 5;          // 0..7
    const int kbase = blockIdx.y * 32;
    const int nbase = blockIdx.x * 32;
#pragma unroll
    for (int r = 0; r < 4; ++r) {
        int k = kbase + ty + r * 8;
        tile[ty + r * 8][nbase + tx - nbase] = f2bf(w[k * NCOLS + nbase + tx]);
    }
    __syncthreads();
    // pack: 128 units = 32 n_local x 4 k8-groups; each unit emits 16B
    const int u = threadIdx.x;
    if (u < 128) {
        const int j8  = u & 3;          // which group of 8 k
        const int nl  = u >> 2;         // 0..31
        s16x8 v;
#pragma unroll
        for (int jj = 0; jj < 8; ++jj)
            v[jj] = tile[j8 * 8 + jj][nl];
        const int n    = nbase + nl;
        const int t    = n >> 4;
        const int c    = blockIdx.y;    // kbase/32
        const int lane = j8 * 16 + (n & 15);
        *(s16x8*)(wp + ((size_t)((t * 32 + c) * 64 + lane)) * 8) = v;
    }
}

// ---- fused 3-gate GEMM + LSTM cell ----
// Block: 512 threads = 8 waves (2M x 4N). Block tile 128x128, 3 gates fused.
// Wave tile 64x32 per gate. BK=32, 64 K-steps over [X|H].
// A: LDS ring-4 x 8KB (swizzled, conflict-free; verified R2-R5).
// B: fragment-packed global -> registers (6 coalesced dwordx4/step/wave),
//    reg-dbuf, L2-resident via XCD-affine grid mapping.
__global__ __launch_bounds__(512, 2)
void lstm_gemm_kernel(const short* __restrict__ Xb, const short* __restrict__ Hb,
                      const short* __restrict__ WP0, const short* __restrict__ WP1,
                      const short* __restrict__ WP2,
                      const short* __restrict__ UP0, const short* __restrict__ UP1,
                      const short* __restrict__ UP2,
                      const float* __restrict__ bf_, const float* __restrict__ bi_,
                      const float* __restrict__ bo_,
                      const float* __restrict__ c0,
                      float* __restrict__ outH, float* __restrict__ outC) {
    __shared__ __align__(16) short lds[4][4096];   // 4 x 8KB A ring

    const int tid  = threadIdx.x;
    const int lane = tid & 63;
    const int wave = tid >> 6;            // 0..7
    const int wm   = wave >> 2;           // 0..1
    const int wn   = wave & 3;            // 0..3
    const int m0   = blockIdx.y * 128;
    const int n0   = blockIdx.x * 128;
    const int bx8  = blockIdx.x * 8;      // n0 >> 4

    const int l15 = lane & 15;
    const int q   = lane >> 4;

    f32x4 acc[3][4][2] = {};   // 96 VGPRs

    // A staging (R5 swizzle, verified conflict-free): thread tid stages slot
    // tid (16B): row tid>>2, chunk-slot tid&3 holds global chunk
    // (tid&3)^((row>>1)&3).
    const int srow  = tid >> 2;                        // 0..127
    const int skoff = ((tid & 3) ^ ((tid >> 3) & 3)) * 8;

    int aOff[4];
#pragma unroll
    for (int m = 0; m < 4; ++m) {
        const int row = wm * 64 + m * 16 + l15;
        aOff[m] = row * 64 + ((q ^ ((row >> 1) & 3)) << 4);
    }

    auto stageA = [&](int buf, int kt) {
        const short* src = (kt >= 32) ? Hb : Xb;
        const char* g = (const char*)(src + (size_t)(m0 + srow) * KDIM +
                                      (kt & 31) * 32 + skoff);
        __builtin_amdgcn_global_load_lds(
            (const __attribute__((address_space(1))) unsigned int*)(uintptr_t)g,
            (__attribute__((address_space(3))) unsigned int*)(uintptr_t)
                ((char*)&lds[buf][0] + tid * 16),
            16, 0, 0);
    };

    bf16x8 fa0[4], fa1[4], fb0[6], fb1[6];

#define LOADB(FB, KT)                                                        \
    {                                                                        \
        const int kt_ = (KT);                                                \
        const bool sec_ = kt_ >= 32;                                         \
        const short* b0_ = sec_ ? UP0 : WP0;                                 \
        const short* b1_ = sec_ ? UP1 : WP1;                                 \
        const short* b2_ = sec_ ? UP2 : WP2;                                 \
        const int c_ = kt_ & 31;                                             \
        _Pragma("unroll")                                                    \
        for (int g_ = 0; g_ < 3; ++g_) {                                     \
            const short* base_ = (g_ == 0) ? b0_ : (g_ == 1 ? b1_ : b2_);    \
            _Pragma("unroll")                                                \
            for (int nf_ = 0; nf_ < 2; ++nf_) {                              \
                const int t_ = bx8 + wn * 2 + nf_;                           \
                FB[g_ * 2 + nf_] = *(const bf16x8*)(base_ +                  \
                    ((size_t)((t_ * 32 + c_) * 64 + lane)) * 8);             \
            }                                                                \
        }                                                                    \
    }

#define READA(FA, BUF)                                                      \
    {                                                                       \
        const char* L_ = (const char*)&lds[(BUF)][0];                       \
        _Pragma("unroll")                                                   \
        for (int m_ = 0; m_ < 4; ++m_)                                      \
            FA[m_] = *(const bf16x8*)(L_ + aOff[m_]);                       \
    }

#define MFMAC(FA, FB)                                                        \
    {                                                                        \
        __builtin_amdgcn_s_setprio(1);                                       \
        _Pragma("unroll")                                                    \
        for (int g_ = 0; g_ < 3; ++g_)                                       \
            _Pragma("unroll")                                                \
            for (int n_ = 0; n_ < 2; ++n_)                                   \
                _Pragma("unroll")                                            \
                for (int m_ = 0; m_ < 4; ++m_)                               \
                    acc[g_][m_][n_] = __builtin_amdgcn_mfma_f32_16x16x32_bf16(\
                        FA[m_], FB[g_ * 2 + n_], acc[g_][m_][n_], 0, 0, 0);  \
        __builtin_amdgcn_s_setprio(0);                                       \
    }

#define WAITV(N) asm volatile("s_waitcnt vmcnt(" #N ")" ::: "memory")
#define WAITL0   asm volatile("s_waitcnt lgkmcnt(0)" ::: "memory")
#define BAR      __builtin_amdgcn_s_barrier()
#define SCHED0   __builtin_amdgcn_sched_barrier(0)

    // prologue. Queue after issue: A0, A1, B0x6, A2  (9 outstanding)
    stageA(0, 0);
    stageA(1, 1);
    LOADB(fb0, 0);
    stageA(2, 2);
    WAITV(8);          // retire A0
    BAR;
    SCHED0;
    READA(fa0, 0);
    WAITL0;

    // main loop. Steady state per phase: issue B(kt+1) [6] + A(kt+3) [1];
    // queue = A(kt+1), B(kt)x6, A(kt+2), B(kt+1)x6, A(kt+3) = 15.
    // WAITV(8) retires A(kt+1) and B(kt) exactly.
    for (int kt = 0; kt < 60; kt += 2) {
        // phase A: MFMA(kt) on set0; prefetch B(kt+1)->fb1, A-frags(kt+1)->fa1
        LOADB(fb1, kt + 1);
        SCHED0;
        stageA((kt + 3) & 3, kt + 3);
        SCHED0;
        WAITV(8);
        BAR;
        SCHED0;
        READA(fa1, (kt + 1) & 3);
        SCHED0;
        MFMAC(fa0, fb0);
        WAITL0;
        // phase B: MFMA(kt+1) on set1; prefetch B(kt+2)->fb0, A(kt+2)->fa0
        LOADB(fb0, kt + 2);
        SCHED0;
        stageA((kt + 4) & 3, kt + 4);
        SCHED0;
        WAITV(8);
        BAR;
        SCHED0;
        READA(fa0, (kt + 2) & 3);
        SCHED0;
        MFMAC(fa1, fb1);
        WAITL0;
    }

    // tail: kt = 60..63
    LOADB(fb1, 61);
    SCHED0;
    stageA(63 & 3, 63);
    SCHED0;
    WAITV(8);          // retire A61, B60   (queue was 15)
    BAR;
    SCHED0;
    READA(fa1, 61 & 3);
    SCHED0;
    MFMAC(fa0, fb0);   // kt=60
    WAITL0;

    LOADB(fb0, 62);
    SCHED0;
    WAITV(7);          // queue 14 -> retire A62, B61
    BAR;
    SCHED0;
    READA(fa0, 62 & 3);
    SCHED0;
    MFMAC(fa1, fb1);   // kt=61
    WAITL0;

    LOADB(fb1, 63);
    SCHED0;
    WAITV(6);          // queue 13 -> retire A63, B62
    BAR;
    SCHED0;
    READA(fa1, 63 & 3);
    SCHED0;
    MFMAC(fa0, fb0);   // kt=62
    WAITL0;

    WAITV(0);          // retire B63
    MFMAC(fa1, fb1);   // kt=63

    // ---- fused LSTM epilogue ----
    const int rj = (lane >> 4) * 4;
#pragma unroll
    for (int m = 0; m < 4; ++m) {
#pragma unroll
        for (int n = 0; n < 2; ++n) {
            const int col = n0 + wn * 32 + n * 16 + l15;
            const float bfv = bf_[col], biv = bi_[col], bov = bo_[col];
            const f32x4 pf = acc[0][m][n];
            const f32x4 pi = acc[1][m][n];
            const f32x4 po = acc[2][m][n];
#pragma unroll
            for (int j = 0; j < 4; ++j) {
                const int row = m0 + wm * 64 + m * 16 + rj + j;
                const float fg = 1.f / (1.f + __expf(-(pf[j] + bfv)));
                const float ig = 1.f / (1.f + __expf(-(pi[j] + biv)));
                const float og = 1.f / (1.f + __expf(-(po[j] + bov)));
                const float cv = c0[row * NCOLS + col];
                const float cn = fg * cv + fg * ig;   // input_cell == forget gate
                const float e  = __expf(-2.f * cn);
                const float th = (1.f - e) / (1.f + e);
                outH[row * NCOLS + col] = og * th;
                outC[row * NCOLS + col] = cn;
            }
        }
    }
#undef LOADB
#undef READA
#undef MFMAC
#undef WAITV
#undef WAITL0
#undef BAR
#undef SCHED0
}

extern "C" void kernel_launch(void* const* d_in, const int* in_sizes, int n_in,
                              void* d_out, int out_size, void* d_ws, size_t ws_size,
                              hipStream_t stream) {
    const float* inputs = (const float*)d_in[0];
    const float* h0     = (const float*)d_in[1];
    const float* c0     = (const float*)d_in[2];
    const float* w_f    = (const float*)d_in[3];
    const float* u_f    = (const float*)d_in[4];
    const float* b_f    = (const float*)d_in[5];
    const float* w_i    = (const float*)d_in[6];
    const float* u_i    = (const float*)d_in[7];
    const float* b_i    = (const float*)d_in[8];
    const float* w_o    = (const float*)d_in[9];
    const float* u_o    = (const float*)d_in[10];
    const float* b_o    = (const float*)d_in[11];

    float* outH = (float*)d_out;
    float* outC = outH + (size_t)MROWS * NCOLS;

    // workspace (bf16): Xb 8MB | Hb 8MB | packed weights 2MB each
    char* ws = (char*)d_ws;
    short* Xb  = (short*)(ws);
    short* Hb  = (short*)(ws + (8u << 20));
    short* WP0 = (short*)(ws + (16u << 20));
    short* WP1 = (short*)(ws + (18u << 20));
    short* WP2 = (short*)(ws + (20u << 20));
    short* UP0 = (short*)(ws + (22u << 20));
    short* UP1 = (short*)(ws + (24u << 20));
    short* UP2 = (short*)(ws + (26u << 20));

    cvt_bf16_kernel<<<4096, 256, 0, stream>>>(inputs, h0, Xb, Hb);

    W6 p;
    p.src[0] = w_f; p.src[1] = w_i; p.src[2] = w_o;
    p.src[3] = u_f; p.src[4] = u_i; p.src[5] = u_o;
    p.dst[0] = WP0; p.dst[1] = WP1; p.dst[2] = WP2;
    p.dst[3] = UP0; p.dst[4] = UP1; p.dst[5] = UP2;
    transpose_cvt_kernel<<<dim3(32, 32, 6), 256, 0, stream>>>(p);

    // grid(8,32): linear id = y*8+x -> id%8 = n-index -> same-n0 blocks land
    // on the same XCD (round-robin dispatch) -> weight slice L2-resident.
    dim3 grid(NCOLS / 128, MROWS / 128);
    lstm_gemm_kernel<<<grid, 512, 0, stream>>>(
        Xb, Hb, WP0, WP1, WP2, UP0, UP1, UP2,
        b_f, b_i, b_o, c0, outH, outC);
}

// Round 8
// 79.450 us; speedup vs baseline: 1.1056x; 1.0081x over previous
//
#include <hip/hip_runtime.h>
#include <cstdint>
#include <cstddef>

// ---------------------------------------------------------------------------
// BasicLSTM fused kernel for MI355X (gfx950) — round 8.
//   pre_g = X @ W_g + H @ U_g + b_g   for g in {f, i, o}
//   c_new = sig(pre_f)*c0 + sig(pre_f)*sig(pre_i)     (input_cell == forget!)
//   h_new = sig(pre_o)*tanh(c_new)
// Round-8 change vs round 5 (B back in LDS; R7's L2-B regressed):
//  - Fine per-phase interleave (T3, m201-template style): each K-step is 3
//    phases {ds-read subtile; stage; BAR; lgkmcnt(0); 8 MFMA (one gate); BAR}.
//    Waves de-phase across the small clusters -> DS pipe and matrix pipe
//    overlap cross-wave instead of alternating in lockstep.
//  - Ring-4 + swizzle + counted vmcnt(8) accounting identical to R5 (proven).
//  WAR safety: stage in step kt targets buf (kt+3)&3; reads target kt&3.
//  Cross-wave: stage of (kt+4)&3 == kt&3 is only issued after the top barrier
//  of step kt+1, which every wave reaches only after its step-kt reads were
//  lgkm-retired -> no overwrite of in-flight reads.
// ---------------------------------------------------------------------------

typedef __attribute__((ext_vector_type(8))) short bf16x8;
typedef __attribute__((ext_vector_type(4))) float f32x4;
typedef __attribute__((ext_vector_type(8))) short s16x8;
typedef __attribute__((ext_vector_type(4))) float f32x4v;

#define MROWS 4096
#define KDIM  1024   // D == S == 1024
#define NCOLS 1024

__device__ __forceinline__ short f2bf(float f) {
    uint32_t u = __builtin_bit_cast(uint32_t, f);
    u += 0x7fffu + ((u >> 16) & 1u);   // round-to-nearest-even
    return (short)(u >> 16);
}

// ---- fp32 -> bf16 for X and H in one launch (32B in / 16B out per thread) --
__global__ void cvt_bf16_kernel(const float* __restrict__ x,
                                const float* __restrict__ h,
                                short* __restrict__ xb,
                                short* __restrict__ hb) {
    int b = blockIdx.x;
    const float* in;
    short* out;
    if (b < 2048) { in = x; out = xb; }
    else          { in = h; out = hb; b -= 2048; }
    const int i = (b * 256 + threadIdx.x) * 8;
    f32x4v a = *(const f32x4v*)(in + i);
    f32x4v c = *(const f32x4v*)(in + i + 4);
    s16x8 o;
    o[0] = f2bf(a[0]); o[1] = f2bf(a[1]); o[2] = f2bf(a[2]); o[3] = f2bf(a[3]);
    o[4] = f2bf(c[0]); o[5] = f2bf(c[1]); o[6] = f2bf(c[2]); o[7] = f2bf(c[3]);
    *(s16x8*)(out + i) = o;
}

// ---- transpose + convert all 6 weights: w [K][N] fp32 -> wt [N][K] bf16 ----
struct W6 {
    const float* src[6];
    short* dst[6];
};

__global__ void transpose_cvt_kernel(W6 p) {
    __shared__ short tile[32][33];
    const float* __restrict__ w  = p.src[blockIdx.z];
    short* __restrict__       wt = p.dst[blockIdx.z];
    const int tx = threadIdx.x & 31;
    const int ty = threadIdx.x >> 5;          // 0..7
    const int kbase = blockIdx.y * 32;
    const int nbase = blockIdx.x * 32;
#pragma unroll
    for (int r = 0; r < 4; ++r) {
        int k = kbase + ty + r * 8;
        tile[ty + r * 8][tx] = f2bf(w[k * NCOLS + nbase + tx]);
    }
    __syncthreads();
#pragma unroll
    for (int r = 0; r < 4; ++r) {
        int n = nbase + ty + r * 8;
        wt[n * KDIM + kbase + tx] = tile[tx][ty + r * 8];
    }
}

// ---- fused 3-gate GEMM + LSTM cell ----
// Block: 512 threads = 8 waves (2M x 4N). Block tile 128x128, 3 gates fused.
// Wave tile 64x32 per gate. BK = 32, 64 K-steps over [X|H] x [W|U].
// 4-deep LDS ring (4 x 32 KB). LDS image per tile r (0=A,1..3=B gate):
// 128 rows x 4 chunks of 16B, chunk slot rotated by (row>>1)&3
// (conflict-free, verified R2-R7: SQ_LDS_BANK_CONFLICT = 0).
__global__ __launch_bounds__(512, 2)
void lstm_gemm_kernel(const short* __restrict__ Xb, const short* __restrict__ Hb,
                      const short* __restrict__ WT0, const short* __restrict__ WT1,
                      const short* __restrict__ WT2,
                      const short* __restrict__ UT0, const short* __restrict__ UT1,
                      const short* __restrict__ UT2,
                      const float* __restrict__ bf_, const float* __restrict__ bi_,
                      const float* __restrict__ bo_,
                      const float* __restrict__ c0,
                      float* __restrict__ outH, float* __restrict__ outC) {
    __shared__ __align__(16) short lds[4][16384];   // 4 x 32 KB ring

    const int tid  = threadIdx.x;
    const int lane = tid & 63;
    const int wave = tid >> 6;            // 0..7
    const int wm   = wave >> 2;           // 0..1
    const int wn   = wave & 3;            // 0..3
    const int m0   = blockIdx.y * 128;
    const int n0   = blockIdx.x * 128;

    const int l15 = lane & 15;
    const int q   = lane >> 4;

    f32x4 acc[3][4][2] = {};   // 96 VGPRs

    const int srow  = tid >> 2;                        // 0..127
    const int skoff = ((tid & 3) ^ ((tid >> 3) & 3)) * 8;

    int aOff[4], bOff[2];
#pragma unroll
    for (int m = 0; m < 4; ++m) {
        const int row = wm * 64 + m * 16 + l15;
        aOff[m] = row * 64 + ((q ^ ((row >> 1) & 3)) << 4);
    }
#pragma unroll
    for (int n = 0; n < 2; ++n) {
        const int row = wn * 32 + n * 16 + l15;
        bOff[n] = row * 64 + ((q ^ ((row >> 1) & 3)) << 4);
    }

    // stage one 16B part r (0=A, 1..3=B gate) of tile kt into buf
    auto stageR = [&](int buf, int kt, int r) {
        const bool second = kt >= 32;
        const short* src;
        int rbase;
        if (r == 0)      { src = second ? Hb  : Xb;  rbase = m0; }
        else if (r == 1) { src = second ? UT0 : WT0; rbase = n0; }
        else if (r == 2) { src = second ? UT1 : WT1; rbase = n0; }
        else             { src = second ? UT2 : WT2; rbase = n0; }
        const char* g = (const char*)(src + (size_t)(rbase + srow) * KDIM +
                                      (kt & 31) * 32 + skoff);
        __builtin_amdgcn_global_load_lds(
            (const __attribute__((address_space(1))) unsigned int*)(uintptr_t)g,
            (__attribute__((address_space(3))) unsigned int*)(uintptr_t)
                ((char*)&lds[buf][0] + r * 8192 + tid * 16),
            16, 0, 0);
    };

#define WAITL0   asm volatile("s_waitcnt lgkmcnt(0)" ::: "memory")
#define BAR      __builtin_amdgcn_s_barrier()
#define SCHED0   __builtin_amdgcn_sched_barrier(0)

#define MFMA8(G, AF, BV0, BV1)                                               \
    {                                                                        \
        __builtin_amdgcn_s_setprio(1);                                       \
        _Pragma("unroll")                                                    \
        for (int m_ = 0; m_ < 4; ++m_)                                       \
            acc[G][m_][0] = __builtin_amdgcn_mfma_f32_16x16x32_bf16(         \
                AF[m_], BV0, acc[G][m_][0], 0, 0, 0);                        \
        _Pragma("unroll")                                                    \
        for (int m_ = 0; m_ < 4; ++m_)                                       \
            acc[G][m_][1] = __builtin_amdgcn_mfma_f32_16x16x32_bf16(         \
                AF[m_], BV1, acc[G][m_][1], 0, 0, 0);                        \
        __builtin_amdgcn_s_setprio(0);                                       \
    }

    // One K-step = 3 fine phases (template structure).
    // DOSTAGE: stage tile KT+3 parts {0,1} in ph0 and {2,3} in ph1.
#define STEP(WVTOK, KT, DOSTAGE)                                             \
    {                                                                        \
        const int kt_ = (KT);                                                \
        const char* L_ = (const char*)&lds[kt_ & 3][0];                      \
        asm volatile("s_waitcnt vmcnt(" WVTOK ")" ::: "memory");             \
        BAR;                           /* all waves' tile-kt loads retired */\
        SCHED0;                                                              \
        /* ---- phase 0: A + B0 reads, stage 0/1, MFMA gate 0 ---- */        \
        bf16x8 af[4], bv0a, bv0b, bv1a, bv1b, bv2a, bv2b;                    \
        _Pragma("unroll")                                                    \
        for (int m_ = 0; m_ < 4; ++m_)                                       \
            af[m_] = *(const bf16x8*)(L_ + aOff[m_]);                        \
        bv0a = *(const bf16x8*)(L_ + 8192 + bOff[0]);                        \
        bv0b = *(const bf16x8*)(L_ + 8192 + bOff[1]);                        \
        if (DOSTAGE) { stageR((kt_ + 3) & 3, kt_ + 3, 0);                    \
                       stageR((kt_ + 3) & 3, kt_ + 3, 1); }                  \
        BAR;                                                                 \
        WAITL0;                                                              \
        SCHED0;                                                              \
        MFMA8(0, af, bv0a, bv0b);                                            \
        BAR;                                                                 \
        SCHED0;                                                              \
        /* ---- phase 1: B1 reads, stage 2/3, MFMA gate 1 ---- */            \
        bv1a = *(const bf16x8*)(L_ + 16384 + bOff[0]);                       \
        bv1b = *(const bf16x8*)(L_ + 16384 + bOff[1]);                       \
        if (DOSTAGE) { stageR((kt_ + 3) & 3, kt_ + 3, 2);                    \
                       stageR((kt_ + 3) & 3, kt_ + 3, 3); }                  \
        BAR;                                                                 \
        WAITL0;                                                              \
        SCHED0;                                                              \
        MFMA8(1, af, bv1a, bv1b);                                            \
        BAR;                                                                 \
        SCHED0;                                                              \
        /* ---- phase 2: B2 reads, MFMA gate 2 ---- */                       \
        bv2a = *(const bf16x8*)(L_ + 24576 + bOff[0]);                       \
        bv2b = *(const bf16x8*)(L_ + 24576 + bOff[1]);                       \
        BAR;                                                                 \
        WAITL0;                                                              \
        SCHED0;                                                              \
        MFMA8(2, af, bv2a, bv2b);                                            \
    }

    // prologue: tiles 0,1,2 in flight (12 loads)
#pragma unroll
    for (int r = 0; r < 4; ++r) stageR(0, 0, r);
#pragma unroll
    for (int r = 0; r < 4; ++r) stageR(1, 1, r);
#pragma unroll
    for (int r = 0; r < 4; ++r) stageR(2, 2, r);

    // main loop: steps 0..60 stage tiles 3..63.
    // vmcnt at step top: outstanding = tiles kt+1 (4) + kt+2 (4) = 8.
    for (int kt = 0; kt <= 60; ++kt) {
        STEP("8", kt, true);
    }
    // tail: 61 (62,63 outstanding = 8), 62 (63 outstanding = 4), 63 (0)
    STEP("8", 61, false);
    STEP("4", 62, false);
    STEP("0", 63, false);

    // ---- fused LSTM epilogue ----
    const int rj = (lane >> 4) * 4;
#pragma unroll
    for (int m = 0; m < 4; ++m) {
#pragma unroll
        for (int n = 0; n < 2; ++n) {
            const int col = n0 + wn * 32 + n * 16 + l15;
            const float bfv = bf_[col], biv = bi_[col], bov = bo_[col];
            const f32x4 pf = acc[0][m][n];
            const f32x4 pi = acc[1][m][n];
            const f32x4 po = acc[2][m][n];
#pragma unroll
            for (int j = 0; j < 4; ++j) {
                const int row = m0 + wm * 64 + m * 16 + rj + j;
                const float fg = 1.f / (1.f + __expf(-(pf[j] + bfv)));
                const float ig = 1.f / (1.f + __expf(-(pi[j] + biv)));
                const float og = 1.f / (1.f + __expf(-(po[j] + bov)));
                const float cv = c0[row * NCOLS + col];
                const float cn = fg * cv + fg * ig;   // input_cell == forget gate
                const float e  = __expf(-2.f * cn);
                const float th = (1.f - e) / (1.f + e);
                outH[row * NCOLS + col] = og * th;
                outC[row * NCOLS + col] = cn;
            }
        }
    }
#undef STEP
#undef MFMA8
#undef WAITL0
#undef BAR
#undef SCHED0
}

extern "C" void kernel_launch(void* const* d_in, const int* in_sizes, int n_in,
                              void* d_out, int out_size, void* d_ws, size_t ws_size,
                              hipStream_t stream) {
    const float* inputs = (const float*)d_in[0];
    const float* h0     = (const float*)d_in[1];
    const float* c0     = (const float*)d_in[2];
    const float* w_f    = (const float*)d_in[3];
    const float* u_f    = (const float*)d_in[4];
    const float* b_f    = (const float*)d_in[5];
    const float* w_i    = (const float*)d_in[6];
    const float* u_i    = (const float*)d_in[7];
    const float* b_i    = (const float*)d_in[8];
    const float* w_o    = (const float*)d_in[9];
    const float* u_o    = (const float*)d_in[10];
    const float* b_o    = (const float*)d_in[11];

    float* outH = (float*)d_out;
    float* outC = outH + (size_t)MROWS * NCOLS;

    // workspace (bf16): Xb 8MB | Hb 8MB | WT0..2 2MB each | UT0..2 2MB each
    char* ws = (char*)d_ws;
    short* Xb  = (short*)(ws);
    short* Hb  = (short*)(ws + (8u << 20));
    short* WT0 = (short*)(ws + (16u << 20));
    short* WT1 = (short*)(ws + (18u << 20));
    short* WT2 = (short*)(ws + (20u << 20));
    short* UT0 = (short*)(ws + (22u << 20));
    short* UT1 = (short*)(ws + (24u << 20));
    short* UT2 = (short*)(ws + (26u << 20));

    cvt_bf16_kernel<<<4096, 256, 0, stream>>>(inputs, h0, Xb, Hb);

    W6 p;
    p.src[0] = w_f; p.src[1] = w_i; p.src[2] = w_o;
    p.src[3] = u_f; p.src[4] = u_i; p.src[5] = u_o;
    p.dst[0] = WT0; p.dst[1] = WT1; p.dst[2] = WT2;
    p.dst[3] = UT0; p.dst[4] = UT1; p.dst[5] = UT2;
    transpose_cvt_kernel<<<dim3(32, 32, 6), 256, 0, stream>>>(p);

    dim3 grid(NCOLS / 128, MROWS / 128);   // (8, 32) = 256 blocks
    lstm_gemm_kernel<<<grid, 512, 0, stream>>>(
        Xb, Hb, WT0, WT1, WT2, UT0, UT1, UT2,
        b_f, b_i, b_o, c0, outH, outC);
}

// Round 9
// 79.327 us; speedup vs baseline: 1.1073x; 1.0015x over previous
//
#include <hip/hip_runtime.h>
#include <cstdint>
#include <cstddef>

// ---------------------------------------------------------------------------
// BasicLSTM fused kernel for MI355X (gfx950) — round 9.
//   pre_g = X @ W_g + H @ U_g + b_g   for g in {f, i, o}
//   c_new = sig(pre_f)*c0 + sig(pre_f)*sig(pre_i)     (input_cell == forget!)
//   h_new = sig(pre_o)*tanh(c_new)
// Round-9 change vs R5-R8: CROSS-BLOCK TLP instead of intra-block scheduling.
//   All R3-R8 schedule variants were flat because grid=256 => 1 block/CU and
//   all 8 waves share one barrier: no independent work hides the drain.
//   m97's 874 TF came from ~3 resident blocks/CU (m114). Restore that:
//   - Block 128x64 (x3 gates), 4 waves, ring-2 LDS 40KB, VGPR<256
//   - grid (16,32) = 512 = 2 blocks/CU; each SIMD hosts 2 waves from
//     DIFFERENT blocks (never co-barriered) -> drain of one overlaps MFMA
//     of the other.
//   - Plain m97 2-barrier loop (__syncthreads), verified swizzle unchanged.
// ---------------------------------------------------------------------------

typedef __attribute__((ext_vector_type(8))) short bf16x8;
typedef __attribute__((ext_vector_type(4))) float f32x4;
typedef __attribute__((ext_vector_type(8))) short s16x8;
typedef __attribute__((ext_vector_type(4))) float f32x4v;

#define MROWS 4096
#define KDIM  1024   // D == S == 1024
#define NCOLS 1024

__device__ __forceinline__ short f2bf(float f) {
    uint32_t u = __builtin_bit_cast(uint32_t, f);
    u += 0x7fffu + ((u >> 16) & 1u);   // round-to-nearest-even
    return (short)(u >> 16);
}

// ---- fp32 -> bf16 for X and H in one launch (32B in / 16B out per thread) --
__global__ void cvt_bf16_kernel(const float* __restrict__ x,
                                const float* __restrict__ h,
                                short* __restrict__ xb,
                                short* __restrict__ hb) {
    int b = blockIdx.x;
    const float* in;
    short* out;
    if (b < 2048) { in = x; out = xb; }
    else          { in = h; out = hb; b -= 2048; }
    const int i = (b * 256 + threadIdx.x) * 8;
    f32x4v a = *(const f32x4v*)(in + i);
    f32x4v c = *(const f32x4v*)(in + i + 4);
    s16x8 o;
    o[0] = f2bf(a[0]); o[1] = f2bf(a[1]); o[2] = f2bf(a[2]); o[3] = f2bf(a[3]);
    o[4] = f2bf(c[0]); o[5] = f2bf(c[1]); o[6] = f2bf(c[2]); o[7] = f2bf(c[3]);
    *(s16x8*)(out + i) = o;
}

// ---- transpose + convert all 6 weights: w [K][N] fp32 -> wt [N][K] bf16 ----
struct W6 {
    const float* src[6];
    short* dst[6];
};

__global__ void transpose_cvt_kernel(W6 p) {
    __shared__ short tile[32][33];
    const float* __restrict__ w  = p.src[blockIdx.z];
    short* __restrict__       wt = p.dst[blockIdx.z];
    const int tx = threadIdx.x & 31;
    const int ty = threadIdx.x >> 5;          // 0..7
    const int kbase = blockIdx.y * 32;
    const int nbase = blockIdx.x * 32;
#pragma unroll
    for (int r = 0; r < 4; ++r) {
        int k = kbase + ty + r * 8;
        tile[ty + r * 8][tx] = f2bf(w[k * NCOLS + nbase + tx]);
    }
    __syncthreads();
#pragma unroll
    for (int r = 0; r < 4; ++r) {
        int n = nbase + ty + r * 8;
        wt[n * KDIM + kbase + tx] = tile[tx][ty + r * 8];
    }
}

// ---- fused 3-gate GEMM + LSTM cell ----
// Block: 256 threads = 4 waves (2M x 2N). Block tile 128 rows x 64 cols,
// 3 gates fused. Wave tile 64x32 per gate: 10 ds_read_b128 / 24 MFMA.
// BK = 32, 64 K-steps over [X|H] x [W|U]. Ring-2 LDS (2 x 20 KB).
// LDS image per buffer: A[128][32] (8KB) | B0[64][32] | B1 | B2 (4KB each),
// rows of 64B = 4 chunks of 16B, chunk slot rotated by (row>>1)&3
// (conflict-free, verified R2-R8: SQ_LDS_BANK_CONFLICT = 0).
__global__ __launch_bounds__(256, 2)
void lstm_gemm_kernel(const short* __restrict__ Xb, const short* __restrict__ Hb,
                      const short* __restrict__ WT0, const short* __restrict__ WT1,
                      const short* __restrict__ WT2,
                      const short* __restrict__ UT0, const short* __restrict__ UT1,
                      const short* __restrict__ UT2,
                      const float* __restrict__ bf_, const float* __restrict__ bi_,
                      const float* __restrict__ bo_,
                      const float* __restrict__ c0,
                      float* __restrict__ outH, float* __restrict__ outC) {
    __shared__ __align__(16) short lds[2][10240];   // 2 x 20 KB ring

    const int tid  = threadIdx.x;
    const int lane = tid & 63;
    const int wave = tid >> 6;            // 0..3
    const int wm   = wave >> 1;           // 0..1  (64-row group)
    const int wn   = wave & 1;            // 0..1  (32-col group)
    const int m0   = blockIdx.y * 128;
    const int n0   = blockIdx.x * 64;

    const int l15 = lane & 15;
    const int q   = lane >> 4;

    f32x4 acc[3][4][2] = {};   // [gate][m][n] = 96 VGPRs

    // staging: thread tid stages 5 x 16B slots per tile:
    //   A rows 0..63  at slot tid        (byte tid*16)
    //   A rows 64..127 at byte 4096+tid*16 (same chunk rotation: +64 rows
    //       shifts (row>>1) by 32 ≡ 0 mod 4)
    //   B_g rows 0..63 at byte 8192+g*4096+tid*16
    // slot: row s>>2, chunk-slot s&3 holds global chunk (s&3)^((row>>1)&3).
    const int srow  = tid >> 2;                        // 0..63
    const int skoff = ((tid & 3) ^ ((tid >> 3) & 3)) * 8;

    int aOff[4], bOff[2];
#pragma unroll
    for (int m = 0; m < 4; ++m) {
        const int row = wm * 64 + m * 16 + l15;
        aOff[m] = row * 64 + ((q ^ ((row >> 1) & 3)) << 4);
    }
#pragma unroll
    for (int n = 0; n < 2; ++n) {
        const int row = wn * 32 + n * 16 + l15;
        bOff[n] = row * 64 + ((q ^ ((row >> 1) & 3)) << 4);
    }

    auto stage = [&](int buf, int kt) {
        const bool second = kt >= 32;
        const short* aS = second ? Hb  : Xb;
        const short* b0 = second ? UT0 : WT0;
        const short* b1 = second ? UT1 : WT1;
        const short* b2 = second ? UT2 : WT2;
        const int kk = (kt & 31) * 32 + skoff;
        char* Lb = (char*)&lds[buf][0];
        const char* gA0 = (const char*)(aS + (size_t)(m0 + srow) * KDIM + kk);
        const char* gA1 = (const char*)(aS + (size_t)(m0 + srow + 64) * KDIM + kk);
        __builtin_amdgcn_global_load_lds(
            (const __attribute__((address_space(1))) unsigned int*)(uintptr_t)gA0,
            (__attribute__((address_space(3))) unsigned int*)(uintptr_t)(Lb + tid * 16),
            16, 0, 0);
        __builtin_amdgcn_global_load_lds(
            (const __attribute__((address_space(1))) unsigned int*)(uintptr_t)gA1,
            (__attribute__((address_space(3))) unsigned int*)(uintptr_t)(Lb + 4096 + tid * 16),
            16, 0, 0);
#pragma unroll
        for (int g = 0; g < 3; ++g) {
            const short* bS = (g == 0) ? b0 : (g == 1 ? b1 : b2);
            const char* gB = (const char*)(bS + (size_t)(n0 + srow) * KDIM + kk);
            __builtin_amdgcn_global_load_lds(
                (const __attribute__((address_space(1))) unsigned int*)(uintptr_t)gB,
                (__attribute__((address_space(3))) unsigned int*)(uintptr_t)
                    (Lb + 8192 + g * 4096 + tid * 16),
                16, 0, 0);
        }
    };

    // m97 2-barrier loop: stage(next) -> read frags(cur) -> MFMA -> sync.
    // __syncthreads drains vmcnt/lgkmcnt; the co-resident INDEPENDENT block
    // on the CU fills the drain with its own MFMAs (cross-block TLP).
    stage(0, 0);
    __syncthreads();

    for (int kt = 0; kt < 64; ++kt) {
        if (kt < 63) stage((kt + 1) & 1, kt + 1);

        const char* L = (const char*)&lds[kt & 1][0];
        bf16x8 af[4];
#pragma unroll
        for (int m = 0; m < 4; ++m)
            af[m] = *(const bf16x8*)(L + aOff[m]);
        __builtin_amdgcn_s_setprio(1);
#pragma unroll
        for (int g = 0; g < 3; ++g) {
#pragma unroll
            for (int n = 0; n < 2; ++n) {
                bf16x8 bv = *(const bf16x8*)(L + 8192 + g * 4096 + bOff[n]);
#pragma unroll
                for (int m = 0; m < 4; ++m)
                    acc[g][m][n] = __builtin_amdgcn_mfma_f32_16x16x32_bf16(
                        af[m], bv, acc[g][m][n], 0, 0, 0);
            }
        }
        __builtin_amdgcn_s_setprio(0);
        __syncthreads();
    }

    // ---- fused LSTM epilogue ----
    const int rj = (lane >> 4) * 4;
#pragma unroll
    for (int m = 0; m < 4; ++m) {
#pragma unroll
        for (int n = 0; n < 2; ++n) {
            const int col = n0 + wn * 32 + n * 16 + l15;
            const float bfv = bf_[col], biv = bi_[col], bov = bo_[col];
            const f32x4 pf = acc[0][m][n];
            const f32x4 pi = acc[1][m][n];
            const f32x4 po = acc[2][m][n];
#pragma unroll
            for (int j = 0; j < 4; ++j) {
                const int row = m0 + wm * 64 + m * 16 + rj + j;
                const float fg = 1.f / (1.f + __expf(-(pf[j] + bfv)));
                const float ig = 1.f / (1.f + __expf(-(pi[j] + biv)));
                const float og = 1.f / (1.f + __expf(-(po[j] + bov)));
                const float cv = c0[row * NCOLS + col];
                const float cn = fg * cv + fg * ig;   // input_cell == forget gate
                const float e  = __expf(-2.f * cn);
                const float th = (1.f - e) / (1.f + e);
                outH[row * NCOLS + col] = og * th;
                outC[row * NCOLS + col] = cn;
            }
        }
    }
}

extern "C" void kernel_launch(void* const* d_in, const int* in_sizes, int n_in,
                              void* d_out, int out_size, void* d_ws, size_t ws_size,
                              hipStream_t stream) {
    const float* inputs = (const float*)d_in[0];
    const float* h0     = (const float*)d_in[1];
    const float* c0     = (const float*)d_in[2];
    const float* w_f    = (const float*)d_in[3];
    const float* u_f    = (const float*)d_in[4];
    const float* b_f    = (const float*)d_in[5];
    const float* w_i    = (const float*)d_in[6];
    const float* u_i    = (const float*)d_in[7];
    const float* b_i    = (const float*)d_in[8];
    const float* w_o    = (const float*)d_in[9];
    const float* u_o    = (const float*)d_in[10];
    const float* b_o    = (const float*)d_in[11];

    float* outH = (float*)d_out;
    float* outC = outH + (size_t)MROWS * NCOLS;

    // workspace (bf16): Xb 8MB | Hb 8MB | WT0..2 2MB each | UT0..2 2MB each
    char* ws = (char*)d_ws;
    short* Xb  = (short*)(ws);
    short* Hb  = (short*)(ws + (8u << 20));
    short* WT0 = (short*)(ws + (16u << 20));
    short* WT1 = (short*)(ws + (18u << 20));
    short* WT2 = (short*)(ws + (20u << 20));
    short* UT0 = (short*)(ws + (22u << 20));
    short* UT1 = (short*)(ws + (24u << 20));
    short* UT2 = (short*)(ws + (26u << 20));

    cvt_bf16_kernel<<<4096, 256, 0, stream>>>(inputs, h0, Xb, Hb);

    W6 p;
    p.src[0] = w_f; p.src[1] = w_i; p.src[2] = w_o;
    p.src[3] = u_f; p.src[4] = u_i; p.src[5] = u_o;
    p.dst[0] = WT0; p.dst[1] = WT1; p.dst[2] = WT2;
    p.dst[3] = UT0; p.dst[4] = UT1; p.dst[5] = UT2;
    transpose_cvt_kernel<<<dim3(32, 32, 6), 256, 0, stream>>>(p);

    // grid (16, 32) = 512 blocks = 2 independent blocks/CU.
    // linear id % 8 = x % 8 -> same-n0 blocks share an XCD: B panels
    // (1.5 MB/XCD) L2-resident.
    dim3 grid(NCOLS / 64, MROWS / 128);
    lstm_gemm_kernel<<<grid, 256, 0, stream>>>(
        Xb, Hb, WT0, WT1, WT2, UT0, UT1, UT2,
        b_f, b_i, b_o, c0, outH, outC);
}

// Round 10
// 76.219 us; speedup vs baseline: 1.1525x; 1.0408x over previous
//
#include <hip/hip_runtime.h>
#include <cstdint>
#include <cstddef>

// ---------------------------------------------------------------------------
// BasicLSTM fused kernel for MI355X (gfx950) — round 10.
//   pre_g = X @ W_g + H @ U_g + b_g   for g in {f, i, o}
//   c_new = sig(pre_f)*c0 + sig(pre_f)*sig(pre_i)     (input_cell == forget!)
//   h_new = sig(pre_o)*tanh(c_new)
// Round-10: port of the proven 256-class 8-phase template (m201 geometry).
//  - One GEMM: Ab[4096][2048] = [X|H] bf16;  Bp[3072][2048] = gate-interleaved
//    packed weights (pcol = (n>>4)*48 + g*16 + (n&15); k: W then U).
//  - Block 256 rows x 192 packed cols, grid 16x16 = 256 = 1 block/CU.
//    8 waves (2Mx4N); per-wave 128 rows x 48 pcols = 8 m-frags x 3 gate-frags
//    -> the 3 n-frags ARE the 3 gates of the same 16 cols: epilogue fused.
//  - BK=64 = 2 k-subs. 4 phases/K-tile: {ds_read frags; stage 1-2 loads;
//    BAR; lgkmcnt(0); 12 MFMA setprio-wrapped; BAR}. 7 staged loads/tile in
//    order {A00,A01,B0lo,B0mid,A10,A11,B1hi}; vmcnt(4)@ph1, vmcnt(3)@ph3 —
//    counted, never 0 in main loop (T3+T4). LDS 2 x 56KB dbuf.
//  - Proven chunk-rotation swizzle per 64B row (0 conflicts R2-R9).
// ---------------------------------------------------------------------------

typedef __attribute__((ext_vector_type(8))) short bf16x8;
typedef __attribute__((ext_vector_type(4))) float f32x4;
typedef __attribute__((ext_vector_type(8))) short s16x8;
typedef __attribute__((ext_vector_type(4))) float f32x4v;

#define MROWS 4096
#define KD    1024
#define KALL  2048
#define NC    1024

__device__ __forceinline__ short f2bf(float f) {
    uint32_t u = __builtin_bit_cast(uint32_t, f);
    u += 0x7fffu + ((u >> 16) & 1u);   // round-to-nearest-even
    return (short)(u >> 16);
}

// ---- X,H fp32 -> Ab[4096][2048] bf16 (X in k 0..1023, H in k 1024..2047) ---
__global__ void cvt_bf16_kernel(const float* __restrict__ x,
                                const float* __restrict__ h,
                                short* __restrict__ ab) {
    int b = blockIdx.x;
    const float* in;
    int coff;
    if (b < 2048) { in = x; coff = 0; }
    else          { in = h; coff = KD; b -= 2048; }
    const int i = (b * 256 + threadIdx.x) * 8;
    const int row = i >> 10, col = i & 1023;
    f32x4v a = *(const f32x4v*)(in + i);
    f32x4v c = *(const f32x4v*)(in + i + 4);
    s16x8 o;
    o[0] = f2bf(a[0]); o[1] = f2bf(a[1]); o[2] = f2bf(a[2]); o[3] = f2bf(a[3]);
    o[4] = f2bf(c[0]); o[5] = f2bf(c[1]); o[6] = f2bf(c[2]); o[7] = f2bf(c[3]);
    *(s16x8*)(ab + (size_t)row * KALL + coff + col) = o;
}

// ---- pack 6 weights into Bp[3072][2048] bf16, gate-interleaved cols -------
struct W6 { const float* src[6]; };

__global__ void pack_w_kernel(W6 p, short* __restrict__ bp) {
    __shared__ short tile[32][33];   // [k_local][n_local]
    const int z = blockIdx.z;                 // 0..5 = wf,wi,wo,uf,ui,uo
    const float* __restrict__ w = p.src[z];
    const int g    = (z < 3) ? z : z - 3;
    const int koff = (z < 3) ? 0 : KD;
    const int tx = threadIdx.x & 31;
    const int ty = threadIdx.x >> 5;          // 0..7
    const int kbase = blockIdx.y * 32;
    const int nbase = blockIdx.x * 32;
#pragma unroll
    for (int r = 0; r < 4; ++r) {
        int k = kbase + ty + r * 8;
        tile[ty + r * 8][tx] = f2bf(w[k * NC + nbase + tx]);
    }
    __syncthreads();
#pragma unroll
    for (int r = 0; r < 4; ++r) {
        const int n = nbase + ty + r * 8;
        const int pcol = ((n >> 4) * 3 + g) * 16 + (n & 15);
        bp[(size_t)pcol * KALL + koff + kbase + tx] = tile[tx][ty + r * 8];
    }
}

// ---- fused 3-gate GEMM + LSTM cell (256x192 8-phase template) -------------
// LDS per buffer (56 KB): A: [ks][mh][128 rows x 64B swz] = 4 x 8KB at 0;
//                         B: [ks][192 rows x 64B swz] = 2 x 12KB at 32768.
// Stage loads per K-tile (order fixed for vmcnt accounting):
//   L0: A ks0 mh0 -> 0      L1: A ks0 mh1 -> 8192
//   L4: B bytes 0..8K -> 32768    L5: B bytes 8..16K -> 40960
//   L2: A ks1 mh0 -> 16384  L3: A ks1 mh1 -> 24576
//   L6: B bytes 16..24K -> 49152
// ph0/ph1 read {L0,L1,L4,L5}; ph2/ph3 read all 7.
__global__ __launch_bounds__(512, 2)
void lstm_gemm_kernel(const short* __restrict__ Ab, const short* __restrict__ Bp,
                      const float* __restrict__ bf_, const float* __restrict__ bi_,
                      const float* __restrict__ bo_,
                      const float* __restrict__ c0,
                      float* __restrict__ outH, float* __restrict__ outC) {
    __shared__ __align__(16) char lds[2][57344];

    const int tid  = threadIdx.x;
    const int lane = tid & 63;
    const int wave = tid >> 6;            // 0..7
    const int wr   = wave >> 2;           // 0..1 (128-row group)
    const int wc   = wave & 3;            // 0..3 (48-pcol group)
    const int m0   = blockIdx.y * 256;
    const int np0  = blockIdx.x * 192;

    const int l15 = lane & 15;
    const int q   = lane >> 4;

    f32x4 acc[8][3] = {};   // [m][gate] = 96 VGPRs

    // ---- staging thread constants (element offsets sans k-tile base) ----
    const int srow = tid >> 2;                              // 0..127
    const int skel = ((tid & 3) ^ ((tid >> 3) & 3)) * 8;    // swizzled k elems
    const short* aPtr[4];   // L index = ks*2 + mh
#pragma unroll
    for (int l = 0; l < 4; ++l) {
        const int ks = l >> 1, mh = l & 1;
        aPtr[l] = Ab + (size_t)(m0 + mh * 128 + srow) * KALL + ks * 32 + skel;
    }
    const short* bPtr[3];
#pragma unroll
    for (int w = 0; w < 3; ++w) {
        const int pbyte = w * 8192 + tid * 16;
        const int ks  = pbyte / 12288;
        const int rem = pbyte - ks * 12288;
        const int row = rem >> 6;
        const int slot = (rem >> 4) & 3;
        bPtr[w] = Bp + (size_t)(np0 + row) * KALL + ks * 32 +
                  ((slot ^ ((row >> 1) & 3)) * 8);
    }

    // ---- read offsets (byte, within a buffer) ----
    int aOffV[8];
#pragma unroll
    for (int m = 0; m < 8; ++m) {
        const int r = m * 16 + l15;                          // 0..127 local
        aOffV[m] = wr * 8192 + r * 64 + ((q ^ ((r >> 1) & 3)) << 4);
    }
    int bOffV[3];
#pragma unroll
    for (int g = 0; g < 3; ++g) {
        const int r = wc * 48 + g * 16 + l15;                // 0..191 local
        bOffV[g] = 32768 + r * 64 + ((q ^ ((r >> 1) & 3)) << 4);
    }

#define GLDS(SRC, DOFF)                                                      \
    __builtin_amdgcn_global_load_lds(                                        \
        (const __attribute__((address_space(1))) unsigned int*)(uintptr_t)(SRC), \
        (__attribute__((address_space(3))) unsigned int*)(uintptr_t)         \
            (Ls + (DOFF) + tid * 16), 16, 0, 0)

#define BAR    __builtin_amdgcn_s_barrier()
#define SCHED0 __builtin_amdgcn_sched_barrier(0)
#define LGKM0  asm volatile("s_waitcnt lgkmcnt(0)" ::: "memory")

#define MFMA12(MB)                                                           \
    {                                                                        \
        __builtin_amdgcn_s_setprio(1);                                       \
        _Pragma("unroll")                                                    \
        for (int mm = 0; mm < 4; ++mm)                                       \
            _Pragma("unroll")                                                \
            for (int g = 0; g < 3; ++g)                                      \
                acc[(MB) + mm][g] = __builtin_amdgcn_mfma_f32_16x16x32_bf16( \
                    af[mm], bg[g], acc[(MB) + mm][g], 0, 0, 0);              \
        __builtin_amdgcn_s_setprio(0);                                       \
    }

    // ---- prologue: issue tile 0's 7 loads in accounting order ----
    {
        char* Ls = lds[0];
        GLDS(aPtr[0], 0);      GLDS(aPtr[1], 8192);
        GLDS(bPtr[0], 32768);  GLDS(bPtr[1], 40960);
        GLDS(aPtr[2], 16384);  GLDS(aPtr[3], 24576);
        GLDS(bPtr[2], 49152);
    }
    asm volatile("s_waitcnt vmcnt(3)" ::: "memory");   // prefix-4 of tile 0
    BAR;

    bf16x8 af[4], bg[3];

    // ---- main loop: tiles 0..30, staging t+1 ----
    for (int t = 0; t < 31; ++t) {
        const char* L = lds[t & 1];
        char* Ls = lds[(t + 1) & 1];
        const int kb = (t + 1) * 64;       // stage k-tile elem base

        // == ph0: A m0..3 ks0 + B ks0 reads; stage L0,L1 ==
#pragma unroll
        for (int mm = 0; mm < 4; ++mm) af[mm] = *(const bf16x8*)(L + aOffV[mm]);
#pragma unroll
        for (int g = 0; g < 3; ++g)    bg[g] = *(const bf16x8*)(L + bOffV[g]);
        GLDS(aPtr[0] + kb, 0);
        GLDS(aPtr[1] + kb, 8192);
        SCHED0;
        BAR;
        LGKM0;
        SCHED0;
        MFMA12(0);
        BAR;

        // == ph1: A m4..7 ks0 reads (B kept in regs); stage L4,L5; vmcnt(4) ==
#pragma unroll
        for (int mm = 0; mm < 4; ++mm)
            af[mm] = *(const bf16x8*)(L + aOffV[4 + mm]);
        GLDS(bPtr[0] + kb, 32768);
        GLDS(bPtr[1] + kb, 40960);
        SCHED0;
        BAR;
        LGKM0;
        SCHED0;
        MFMA12(4);
        asm volatile("s_waitcnt vmcnt(4)" ::: "memory");  // tile t fully landed
        BAR;

        // == ph2: A m0..3 ks1 + B ks1 reads; stage L2,L3 ==
#pragma unroll
        for (int mm = 0; mm < 4; ++mm)
            af[mm] = *(const bf16x8*)(L + 16384 + aOffV[mm]);
#pragma unroll
        for (int g = 0; g < 3; ++g)
            bg[g] = *(const bf16x8*)(L + 12288 + bOffV[g]);
        GLDS(aPtr[2] + kb, 16384);
        GLDS(aPtr[3] + kb, 24576);
        SCHED0;
        BAR;
        LGKM0;
        SCHED0;
        MFMA12(0);
        BAR;

        // == ph3: A m4..7 ks1 reads; stage L6; vmcnt(3) ==
#pragma unroll
        for (int mm = 0; mm < 4; ++mm)
            af[mm] = *(const bf16x8*)(L + 16384 + aOffV[4 + mm]);
        GLDS(bPtr[2] + kb, 49152);
        SCHED0;
        BAR;
        LGKM0;
        SCHED0;
        MFMA12(4);
        asm volatile("s_waitcnt vmcnt(3)" ::: "memory");  // t+1 prefix-4 landed
        BAR;
    }

    // ---- tail: tile 31, no staging ----
    {
        const char* L = lds[1];
        // ph0
#pragma unroll
        for (int mm = 0; mm < 4; ++mm) af[mm] = *(const bf16x8*)(L + aOffV[mm]);
#pragma unroll
        for (int g = 0; g < 3; ++g)    bg[g] = *(const bf16x8*)(L + bOffV[g]);
        SCHED0; BAR; LGKM0; SCHED0;
        MFMA12(0);
        BAR;
        // ph1 (+ drain remaining 3 loads of tile 31)
#pragma unroll
        for (int mm = 0; mm < 4; ++mm)
            af[mm] = *(const bf16x8*)(L + aOffV[4 + mm]);
        SCHED0; BAR; LGKM0; SCHED0;
        MFMA12(4);
        asm volatile("s_waitcnt vmcnt(0)" ::: "memory");
        BAR;
        // ph2
#pragma unroll
        for (int mm = 0; mm < 4; ++mm)
            af[mm] = *(const bf16x8*)(L + 16384 + aOffV[mm]);
#pragma unroll
        for (int g = 0; g < 3; ++g)
            bg[g] = *(const bf16x8*)(L + 12288 + bOffV[g]);
        SCHED0; BAR; LGKM0; SCHED0;
        MFMA12(0);
        BAR;
        // ph3
#pragma unroll
        for (int mm = 0; mm < 4; ++mm)
            af[mm] = *(const bf16x8*)(L + 16384 + aOffV[4 + mm]);
        LGKM0; SCHED0;
        MFMA12(4);
    }

    // ---- fused LSTM epilogue ----
    const int rj  = q * 4;
    const int col = blockIdx.x * 64 + wc * 16 + l15;
    const float bfv = bf_[col], biv = bi_[col], bov = bo_[col];
#pragma unroll
    for (int m = 0; m < 8; ++m) {
        const f32x4 pf = acc[m][0];
        const f32x4 pi = acc[m][1];
        const f32x4 po = acc[m][2];
#pragma unroll
        for (int j = 0; j < 4; ++j) {
            const int row = m0 + wr * 128 + m * 16 + rj + j;
            const float fg = 1.f / (1.f + __expf(-(pf[j] + bfv)));
            const float ig = 1.f / (1.f + __expf(-(pi[j] + biv)));
            const float og = 1.f / (1.f + __expf(-(po[j] + bov)));
            const float cv = c0[row * NC + col];
            const float cn = fg * cv + fg * ig;   // input_cell == forget gate
            const float e  = __expf(-2.f * cn);
            const float th = (1.f - e) / (1.f + e);
            outH[row * NC + col] = og * th;
            outC[row * NC + col] = cn;
        }
    }
#undef GLDS
#undef BAR
#undef SCHED0
#undef LGKM0
#undef MFMA12
}

extern "C" void kernel_launch(void* const* d_in, const int* in_sizes, int n_in,
                              void* d_out, int out_size, void* d_ws, size_t ws_size,
                              hipStream_t stream) {
    const float* inputs = (const float*)d_in[0];
    const float* h0     = (const float*)d_in[1];
    const float* c0     = (const float*)d_in[2];
    const float* w_f    = (const float*)d_in[3];
    const float* u_f    = (const float*)d_in[4];
    const float* b_f    = (const float*)d_in[5];
    const float* w_i    = (const float*)d_in[6];
    const float* u_i    = (const float*)d_in[7];
    const float* b_i    = (const float*)d_in[8];
    const float* w_o    = (const float*)d_in[9];
    const float* u_o    = (const float*)d_in[10];
    const float* b_o    = (const float*)d_in[11];

    float* outH = (float*)d_out;
    float* outC = outH + (size_t)MROWS * NC;

    // workspace: Ab (16MB bf16) | Bp (12MB bf16)
    char* ws = (char*)d_ws;
    short* Ab = (short*)(ws);
    short* Bp = (short*)(ws + (16u << 20));

    cvt_bf16_kernel<<<4096, 256, 0, stream>>>(inputs, h0, Ab);

    W6 p;
    p.src[0] = w_f; p.src[1] = w_i; p.src[2] = w_o;
    p.src[3] = u_f; p.src[4] = u_i; p.src[5] = u_o;
    pack_w_kernel<<<dim3(32, 32, 6), 256, 0, stream>>>(p, Bp);

    // grid 16x16 = 256 blocks = 1/CU; id%8 = bx%8 -> same-B-panel blocks
    // share an XCD (B panel 768KB L2-resident).
    dim3 grid(16, 16);
    lstm_gemm_kernel<<<grid, 512, 0, stream>>>(
        Ab, Bp, b_f, b_i, b_o, c0, outH, outC);
}

// Round 11
// 73.010 us; speedup vs baseline: 1.2032x; 1.0440x over previous
//
#include <hip/hip_runtime.h>
#include <cstdint>
#include <cstddef>

// ---------------------------------------------------------------------------
// BasicLSTM fused kernel for MI355X (gfx950) — round 11.
//   pre_g = X @ W_g + H @ U_g + b_g   for g in {f, i, o}
//   c_new = sig(pre_f)*c0 + sig(pre_f)*sig(pre_i)     (input_cell == forget!)
//   h_new = sig(pre_o)*tanh(c_new)
// Round-11 vs R10 (same 256x192 packed geometry, two fixes):
//  - 2 phases per K-tile (one per k-sub), 24-MFMA clusters, ONE barrier per
//    phase: [vmcnt(N); BAR; 11 ds_reads; stage 3-4 loads; lgkm0; MFMA24].
//    WAR-safe: a wave reaches the barrier only after lgkm-retiring its
//    previous phase's reads; stage is issued after the barrier.
//  - Consumption-side counted vmcnt: p0 entry vmcnt(3) needs loads issued
//    2 phases earlier (~2600 cyc slack); p1 entry vmcnt(4) likewise.
//    R10 demanded next-tile loads 1-2 phases after issue -> stall per tile.
//  Steady state: 7 loads outstanding, never below 3 in the main loop (T4).
// ---------------------------------------------------------------------------

typedef __attribute__((ext_vector_type(8))) short bf16x8;
typedef __attribute__((ext_vector_type(4))) float f32x4;
typedef __attribute__((ext_vector_type(8))) short s16x8;
typedef __attribute__((ext_vector_type(4))) float f32x4v;

#define MROWS 4096
#define KD    1024
#define KALL  2048
#define NC    1024

__device__ __forceinline__ short f2bf(float f) {
    uint32_t u = __builtin_bit_cast(uint32_t, f);
    u += 0x7fffu + ((u >> 16) & 1u);   // round-to-nearest-even
    return (short)(u >> 16);
}

// ---- X,H fp32 -> Ab[4096][2048] bf16 (X in k 0..1023, H in k 1024..2047) ---
__global__ void cvt_bf16_kernel(const float* __restrict__ x,
                                const float* __restrict__ h,
                                short* __restrict__ ab) {
    int b = blockIdx.x;
    const float* in;
    int coff;
    if (b < 2048) { in = x; coff = 0; }
    else          { in = h; coff = KD; b -= 2048; }
    const int i = (b * 256 + threadIdx.x) * 8;
    const int row = i >> 10, col = i & 1023;
    f32x4v a = *(const f32x4v*)(in + i);
    f32x4v c = *(const f32x4v*)(in + i + 4);
    s16x8 o;
    o[0] = f2bf(a[0]); o[1] = f2bf(a[1]); o[2] = f2bf(a[2]); o[3] = f2bf(a[3]);
    o[4] = f2bf(c[0]); o[5] = f2bf(c[1]); o[6] = f2bf(c[2]); o[7] = f2bf(c[3]);
    *(s16x8*)(ab + (size_t)row * KALL + coff + col) = o;
}

// ---- pack 6 weights into Bp[3072][2048] bf16, gate-interleaved cols -------
struct W6 { const float* src[6]; };

__global__ void pack_w_kernel(W6 p, short* __restrict__ bp) {
    __shared__ short tile[32][33];   // [k_local][n_local]
    const int z = blockIdx.z;                 // 0..5 = wf,wi,wo,uf,ui,uo
    const float* __restrict__ w = p.src[z];
    const int g    = (z < 3) ? z : z - 3;
    const int koff = (z < 3) ? 0 : KD;
    const int tx = threadIdx.x & 31;
    const int ty = threadIdx.x >> 5;          // 0..7
    const int kbase = blockIdx.y * 32;
    const int nbase = blockIdx.x * 32;
#pragma unroll
    for (int r = 0; r < 4; ++r) {
        int k = kbase + ty + r * 8;
        tile[ty + r * 8][tx] = f2bf(w[k * NC + nbase + tx]);
    }
    __syncthreads();
#pragma unroll
    for (int r = 0; r < 4; ++r) {
        const int n = nbase + ty + r * 8;
        const int pcol = ((n >> 4) * 3 + g) * 16 + (n & 15);
        bp[(size_t)pcol * KALL + koff + kbase + tx] = tile[tx][ty + r * 8];
    }
}

// ---- fused 3-gate GEMM + LSTM cell (256x192, 2-phase/K-tile) --------------
// LDS per buffer (56 KB): A: [ks][mh][128 rows x 64B swz] = 4 x 8KB at 0;
//                         B: [ks][192 rows x 64B swz] = 2 x 12KB at 32768.
// Stage loads per K-tile (accounting order):
//   p0 issues: L0: A ks0 mh0 -> 0      L1: A ks0 mh1 -> 8192
//              L4: B bytes 0..8K -> 32768   L5: B bytes 8..16K -> 40960
//   p1 issues: L2: A ks1 mh0 -> 16384  L3: A ks1 mh1 -> 24576
//              L6: B bytes 16..24K -> 49152
// p0 consumes {L0,L1,L4,L5}; p1 consumes {L2,L3,L5,L6} (L5 retired at p0).
__global__ __launch_bounds__(512, 2)
void lstm_gemm_kernel(const short* __restrict__ Ab, const short* __restrict__ Bp,
                      const float* __restrict__ bf_, const float* __restrict__ bi_,
                      const float* __restrict__ bo_,
                      const float* __restrict__ c0,
                      float* __restrict__ outH, float* __restrict__ outC) {
    __shared__ __align__(16) char lds[2][57344];

    const int tid  = threadIdx.x;
    const int lane = tid & 63;
    const int wave = tid >> 6;            // 0..7
    const int wr   = wave >> 2;           // 0..1 (128-row group)
    const int wc   = wave & 3;            // 0..3 (48-pcol group)
    const int m0   = blockIdx.y * 256;
    const int np0  = blockIdx.x * 192;

    const int l15 = lane & 15;
    const int q   = lane >> 4;

    f32x4 acc[8][3] = {};   // [m][gate] = 96 VGPRs

    // ---- staging thread constants ----
    const int srow = tid >> 2;                              // 0..127
    const int skel = ((tid & 3) ^ ((tid >> 3) & 3)) * 8;    // swizzled k elems
    const short* aPtr[4];   // index = ks*2 + mh
#pragma unroll
    for (int l = 0; l < 4; ++l) {
        const int ks = l >> 1, mh = l & 1;
        aPtr[l] = Ab + (size_t)(m0 + mh * 128 + srow) * KALL + ks * 32 + skel;
    }
    const short* bPtr[3];
#pragma unroll
    for (int w = 0; w < 3; ++w) {
        const int pbyte = w * 8192 + tid * 16;
        const int ks  = pbyte / 12288;
        const int rem = pbyte - ks * 12288;
        const int row = rem >> 6;
        const int slot = (rem >> 4) & 3;
        bPtr[w] = Bp + (size_t)(np0 + row) * KALL + ks * 32 +
                  ((slot ^ ((row >> 1) & 3)) * 8);
    }

    // ---- read offsets (byte, within a buffer; ks0 base) ----
    int aOffV[8];
#pragma unroll
    for (int m = 0; m < 8; ++m) {
        const int r = m * 16 + l15;
        aOffV[m] = wr * 8192 + r * 64 + ((q ^ ((r >> 1) & 3)) << 4);
    }
    int bOffV[3];
#pragma unroll
    for (int g = 0; g < 3; ++g) {
        const int r = wc * 48 + g * 16 + l15;
        bOffV[g] = 32768 + r * 64 + ((q ^ ((r >> 1) & 3)) << 4);
    }

#define GLDS(SRC, DOFF)                                                      \
    __builtin_amdgcn_global_load_lds(                                        \
        (const __attribute__((address_space(1))) unsigned int*)(uintptr_t)(SRC), \
        (__attribute__((address_space(3))) unsigned int*)(uintptr_t)         \
            (Ls + (DOFF) + tid * 16), 16, 0, 0)

#define BAR    __builtin_amdgcn_s_barrier()
#define SCHED0 __builtin_amdgcn_sched_barrier(0)
#define LGKM0  asm volatile("s_waitcnt lgkmcnt(0)" ::: "memory")
#define WAITV(N) asm volatile("s_waitcnt vmcnt(" #N ")" ::: "memory")

#define MFMA24(AF, BG)                                                       \
    {                                                                        \
        __builtin_amdgcn_s_setprio(1);                                       \
        _Pragma("unroll")                                                    \
        for (int mm = 0; mm < 8; ++mm)                                       \
            _Pragma("unroll")                                                \
            for (int g = 0; g < 3; ++g)                                      \
                acc[mm][g] = __builtin_amdgcn_mfma_f32_16x16x32_bf16(        \
                    AF[mm], BG[g], acc[mm][g], 0, 0, 0);                     \
        __builtin_amdgcn_s_setprio(0);                                       \
    }

    // ---- prologue: tile 0's 7 loads in accounting order ----
    {
        char* Ls = lds[0];
        GLDS(aPtr[0], 0);      GLDS(aPtr[1], 8192);
        GLDS(bPtr[0], 32768);  GLDS(bPtr[1], 40960);
        GLDS(aPtr[2], 16384);  GLDS(aPtr[3], 24576);
        GLDS(bPtr[2], 49152);
    }

    bf16x8 af[8], bg[3];

    // ---- main loop: tiles 0..30, staging t+1 ----
    // Steady state per wave: 7 loads outstanding at each phase entry.
    for (int t = 0; t < 31; ++t) {
        const char* L = lds[t & 1];
        char* Ls = lds[(t + 1) & 1];
        const int kb = (t + 1) * 64;

        // == p0: ks0 ==   (needs L0,L1,L4,L5 of t; 3 younger outstanding)
        WAITV(3);
        BAR;
        SCHED0;
#pragma unroll
        for (int mm = 0; mm < 8; ++mm) af[mm] = *(const bf16x8*)(L + aOffV[mm]);
#pragma unroll
        for (int g = 0; g < 3; ++g)    bg[g] = *(const bf16x8*)(L + bOffV[g]);
        GLDS(aPtr[0] + kb, 0);
        GLDS(aPtr[1] + kb, 8192);
        GLDS(bPtr[0] + kb, 32768);
        GLDS(bPtr[1] + kb, 40960);
        SCHED0;
        LGKM0;
        SCHED0;
        MFMA24(af, bg);

        // == p1: ks1 ==   (needs L2,L3,L6 of t; 4 younger outstanding)
        WAITV(4);
        BAR;
        SCHED0;
#pragma unroll
        for (int mm = 0; mm < 8; ++mm)
            af[mm] = *(const bf16x8*)(L + 16384 + aOffV[mm]);
#pragma unroll
        for (int g = 0; g < 3; ++g)
            bg[g] = *(const bf16x8*)(L + 12288 + bOffV[g]);
        GLDS(aPtr[2] + kb, 16384);
        GLDS(aPtr[3] + kb, 24576);
        GLDS(bPtr[2] + kb, 49152);
        SCHED0;
        LGKM0;
        SCHED0;
        MFMA24(af, bg);
    }

    // ---- tail: tile 31, no staging ----
    {
        const char* L = lds[1];
        WAITV(3);
        BAR;
        SCHED0;
#pragma unroll
        for (int mm = 0; mm < 8; ++mm) af[mm] = *(const bf16x8*)(L + aOffV[mm]);
#pragma unroll
        for (int g = 0; g < 3; ++g)    bg[g] = *(const bf16x8*)(L + bOffV[g]);
        LGKM0;
        SCHED0;
        MFMA24(af, bg);

        WAITV(0);
        BAR;
        SCHED0;
#pragma unroll
        for (int mm = 0; mm < 8; ++mm)
            af[mm] = *(const bf16x8*)(L + 16384 + aOffV[mm]);
#pragma unroll
        for (int g = 0; g < 3; ++g)
            bg[g] = *(const bf16x8*)(L + 12288 + bOffV[g]);
        LGKM0;
        SCHED0;
        MFMA24(af, bg);
    }

    // ---- fused LSTM epilogue ----
    const int rj  = q * 4;
    const int col = blockIdx.x * 64 + wc * 16 + l15;
    const float bfv = bf_[col], biv = bi_[col], bov = bo_[col];
#pragma unroll
    for (int m = 0; m < 8; ++m) {
        const f32x4 pf = acc[m][0];
        const f32x4 pi = acc[m][1];
        const f32x4 po = acc[m][2];
#pragma unroll
        for (int j = 0; j < 4; ++j) {
            const int row = m0 + wr * 128 + m * 16 + rj + j;
            const float fg = 1.f / (1.f + __expf(-(pf[j] + bfv)));
            const float ig = 1.f / (1.f + __expf(-(pi[j] + biv)));
            const float og = 1.f / (1.f + __expf(-(po[j] + bov)));
            const float cv = c0[row * NC + col];
            const float cn = fg * cv + fg * ig;   // input_cell == forget gate
            const float e  = __expf(-2.f * cn);
            const float th = (1.f - e) / (1.f + e);
            outH[row * NC + col] = og * th;
            outC[row * NC + col] = cn;
        }
    }
#undef GLDS
#undef BAR
#undef SCHED0
#undef LGKM0
#undef WAITV
#undef MFMA24
}

extern "C" void kernel_launch(void* const* d_in, const int* in_sizes, int n_in,
                              void* d_out, int out_size, void* d_ws, size_t ws_size,
                              hipStream_t stream) {
    const float* inputs = (const float*)d_in[0];
    const float* h0     = (const float*)d_in[1];
    const float* c0     = (const float*)d_in[2];
    const float* w_f    = (const float*)d_in[3];
    const float* u_f    = (const float*)d_in[4];
    const float* b_f    = (const float*)d_in[5];
    const float* w_i    = (const float*)d_in[6];
    const float* u_i    = (const float*)d_in[7];
    const float* b_i    = (const float*)d_in[8];
    const float* w_o    = (const float*)d_in[9];
    const float* u_o    = (const float*)d_in[10];
    const float* b_o    = (const float*)d_in[11];

    float* outH = (float*)d_out;
    float* outC = outH + (size_t)MROWS * NC;

    // workspace: Ab (16MB bf16) | Bp (12MB bf16)
    char* ws = (char*)d_ws;
    short* Ab = (short*)(ws);
    short* Bp = (short*)(ws + (16u << 20));

    cvt_bf16_kernel<<<4096, 256, 0, stream>>>(inputs, h0, Ab);

    W6 p;
    p.src[0] = w_f; p.src[1] = w_i; p.src[2] = w_o;
    p.src[3] = u_f; p.src[4] = u_i; p.src[5] = u_o;
    pack_w_kernel<<<dim3(32, 32, 6), 256, 0, stream>>>(p, Bp);

    // grid 16x16 = 256 blocks = 1/CU; id%8 = bx%8 -> same-B-panel blocks
    // share an XCD (B panel 768KB L2-resident).
    dim3 grid(16, 16);
    lstm_gemm_kernel<<<grid, 512, 0, stream>>>(
        Ab, Bp, b_f, b_i, b_o, c0, outH, outC);
}